// Round 5
// baseline (4019.761 us; speedup 1.0000x reference)
//
#include <hip/hip_runtime.h>
#include <cstddef>
#include <cstdint>

// Problem constants
#define TT 256
#define BB 64
#define NTAG 34
// M = TT*BB = 16384

__device__ __forceinline__ float sigf(float x) { return 1.0f / (1.0f + expf(-x)); }

// ---------------------------------------------------------------------------
// fp32 tiled GEMM: out[m][n] = sum_k A[m][k] * W[n][k] + biasA[n] (+ biasB[n])
// (unchanged; ~750 us total across 3 calls)
// ---------------------------------------------------------------------------
__global__ __launch_bounds__(256) void gemm_k(
    const float* __restrict__ Abase, const int* __restrict__ gidx,
    const float* __restrict__ W, const float* __restrict__ biasA,
    const float* __restrict__ biasB, float* __restrict__ out,
    int M, int K, int Nvalid, int xp_mode) {
  __shared__ float As[32][68];
  __shared__ float Bs[32][68];
  int tid = threadIdx.x;
  int m0 = blockIdx.x * 64;
  int n0 = blockIdx.y * 64;
  int tx = tid & 15, ty = tid >> 4;
  int lk = (tid & 7) * 4;
  int lr = tid >> 3;

  float acc[4][4] = {};

  const float* arow0;
  const float* arow1;
  {
    int ma = m0 + lr, mb = m0 + lr + 32;
    size_t ra = gidx ? (size_t)gidx[ma] : (size_t)ma;
    size_t rb = gidx ? (size_t)gidx[mb] : (size_t)mb;
    arow0 = Abase + ra * (size_t)K;
    arow1 = Abase + rb * (size_t)K;
  }
  int nA = n0 + lr, nB = n0 + lr + 32;
  const float* wr0 = W + (size_t)nA * K;
  const float* wr1 = W + (size_t)nB * K;
  bool v0 = nA < Nvalid, v1 = nB < Nvalid;

  for (int k0 = 0; k0 < K; k0 += 32) {
    float4 a0 = *(const float4*)(arow0 + k0 + lk);
    float4 a1 = *(const float4*)(arow1 + k0 + lk);
    float4 b0 = v0 ? *(const float4*)(wr0 + k0 + lk) : make_float4(0, 0, 0, 0);
    float4 b1 = v1 ? *(const float4*)(wr1 + k0 + lk) : make_float4(0, 0, 0, 0);
    __syncthreads();
    As[lk + 0][lr] = a0.x; As[lk + 1][lr] = a0.y; As[lk + 2][lr] = a0.z; As[lk + 3][lr] = a0.w;
    As[lk + 0][lr + 32] = a1.x; As[lk + 1][lr + 32] = a1.y; As[lk + 2][lr + 32] = a1.z; As[lk + 3][lr + 32] = a1.w;
    Bs[lk + 0][lr] = b0.x; Bs[lk + 1][lr] = b0.y; Bs[lk + 2][lr] = b0.z; Bs[lk + 3][lr] = b0.w;
    Bs[lk + 0][lr + 32] = b1.x; Bs[lk + 1][lr + 32] = b1.y; Bs[lk + 2][lr + 32] = b1.z; Bs[lk + 3][lr + 32] = b1.w;
    __syncthreads();
#pragma unroll
    for (int k = 0; k < 32; ++k) {
      float4 av = *(const float4*)&As[k][ty * 4];
      float4 bv = *(const float4*)&Bs[k][tx * 4];
#pragma unroll
      for (int i = 0; i < 4; ++i) {
        float a = (&av.x)[i];
        acc[i][0] += a * bv.x;
        acc[i][1] += a * bv.y;
        acc[i][2] += a * bv.z;
        acc[i][3] += a * bv.w;
      }
    }
  }
#pragma unroll
  for (int i = 0; i < 4; ++i) {
    int m = m0 + ty * 4 + i;
#pragma unroll
    for (int j = 0; j < 4; ++j) {
      int n = n0 + tx * 4 + j;
      if (n < Nvalid) {
        float v = acc[i][j] + biasA[n] + (biasB ? biasB[n] : 0.0f);
        if (xp_mode)
          out[((size_t)(n >> 10) * M + m) * 1024 + (n & 1023)] = v;
        else
          out[(size_t)m * Nvalid + n] = v;
      }
    }
  }
}

// ---------------------------------------------------------------------------
// Register-stationary LSTM recurrence, v4 (congestion-reduced packet exchange).
// 256 blocks x 512 threads = 2 dir x 8 unit-slices(32 units) x 16 bg(4 batch).
// Exchange medium is L3 (agent-scope atomics' coherence point: per-XCD L2s
// are not cross-coherent) so per-trip latency is ~700-900 cyc and POLL
// TRAFFIC is the enemy. v4 changes vs v3:
//  1. Only 2 waves (threads 0-127) poll; 8 packets each, all 8 loads in
//     flight per iteration -> 4x less L3 poll traffic, one-latency detect.
//  2. Own-slice h bypasses L3: gate lanes write next-step LDS directly;
//     pollers skip the own-js range.
//  3. Packet store issued BEFORE the scattered out store.
//  4. hS/xgS double-buffered -> single __syncthreads per step.
// ---------------------------------------------------------------------------
__global__ __launch_bounds__(512) void lstm_fused4(
    const float* __restrict__ xp,    // [2][M][1024]
    const float* __restrict__ whh,   // [2][1024][256]
    const int* __restrict__ lengths,
    float* __restrict__ out,         // [M][512]
    unsigned long long* hx,          // [2 slot][2 d][16 bg][1024 packets]
    int T, int B) {
  __shared__ float4 hS[2][256];   // [parity][k] x 4 batches
  __shared__ float xgS[2][512];   // [parity][b][g][jl]
  int blk = blockIdx.x;
  int js = blk >> 5;
  int inner = blk & 31;
  int d = inner >> 4;
  int bg = inner & 15;
  int tid = threadIdx.x;
  int jl = tid >> 4, kseg = tid & 15;
  int j = js * 32 + jl;
  size_t M = (size_t)T * B;
  int b0 = bg * 4;

  // Stationary weights: w[g][i] = whh[d][g*256+j][kseg+16i]
  float w[4][16];
#pragma unroll
  for (int g = 0; g < 4; ++g) {
    const float* wr = whh + ((size_t)d * 1024 + g * 256 + j) * 256 + kseg;
#pragma unroll
    for (int i = 0; i < 16; ++i) w[g][i] = wr[16 * i];
  }

  int batch = b0 + (kseg & 3);
  int len = lengths[batch];
  float cst = 0.0f, hst = 0.0f;

  unsigned long long* hx_grp = hx + ((size_t)d * 16 + bg) * 1024;
  const size_t slotStride = (size_t)2 * 16 * 1024;  // packets per slot

  // xg loader mapping: tid -> (lb, lg, lj)
  int lb = tid >> 7, lg = (tid >> 5) & 3, lj = tid & 31;
  const float* xg_base = xp + (size_t)d * M * 1024 + (size_t)lg * 256 + js * 32 + lj;

  bool poller = (tid < 128) && ((tid >> 4) != js);

  for (int s = 0; s < T; ++s) {
    int par = s & 1;
    int t = d ? (T - 1 - s) : s;
    // xp gate bias for this step (h-independent; overlaps poll latency)
    float xv = xg_base[((size_t)t * B + b0 + lb) * 1024];
    if (s == 0) {
      if (tid < 256) hS[0][tid] = make_float4(0.f, 0.f, 0.f, 0.f);
    } else if (poller) {
      const unsigned long long* src = hx_grp + (size_t)par * slotStride + (size_t)tid * 8;
      unsigned int want = (unsigned int)s;
      unsigned long long p[8];
      int guard = 0;
      bool ok = false;
      while (!ok && ++guard < (1 << 20)) {
#pragma unroll
        for (int q = 0; q < 8; ++q)
          p[q] = __hip_atomic_load(src + q, __ATOMIC_RELAXED, __HIP_MEMORY_SCOPE_AGENT);
        ok = true;
#pragma unroll
        for (int q = 0; q < 8; ++q) ok &= ((unsigned int)(p[q] >> 32) == want);
      }
      float* hf = (float*)&hS[par][0];
#pragma unroll
      for (int q = 0; q < 8; ++q)
        hf[tid * 8 + q] = __uint_as_float((unsigned int)p[q]);
    }
    xgS[par][tid] = xv;
    __syncthreads();  // the only barrier per step

    // GEMV over my 16 k values for 4 gates x 4 batches
    float acc[4][4];
#pragma unroll
    for (int g = 0; g < 4; ++g)
#pragma unroll
      for (int b = 0; b < 4; ++b) acc[g][b] = 0.0f;
#pragma unroll
    for (int i = 0; i < 16; ++i) {
      float4 hv = hS[par][kseg + 16 * i];
#pragma unroll
      for (int g = 0; g < 4; ++g) {
        acc[g][0] += w[g][i] * hv.x;
        acc[g][1] += w[g][i] * hv.y;
        acc[g][2] += w[g][i] * hv.z;
        acc[g][3] += w[g][i] * hv.w;
      }
    }
    // Butterfly over the 16 kseg lanes -> every lane holds full sums
#pragma unroll
    for (int g = 0; g < 4; ++g)
#pragma unroll
      for (int b = 0; b < 4; ++b) {
        float v = acc[g][b];
        v += __shfl_xor(v, 1);
        v += __shfl_xor(v, 2);
        v += __shfl_xor(v, 4);
        v += __shfl_xor(v, 8);
        acc[g][b] = v;
      }

    if (kseg < 4) {
      int b = kseg;
      float ig = sigf(acc[0][b] + xgS[par][b * 128 + 0 * 32 + jl]);
      float fg = sigf(acc[1][b] + xgS[par][b * 128 + 1 * 32 + jl]);
      float gg = tanhf(acc[2][b] + xgS[par][b * 128 + 2 * 32 + jl]);
      float og = sigf(acc[3][b] + xgS[par][b * 128 + 3 * 32 + jl]);
      bool m = t < len;
      float cn = fg * cst + ig * gg;
      float hn = og * tanhf(cn);
      if (m) { cst = cn; hst = hn; }
      if (s + 1 < T) {
        // critical store first: stamp-embedded 8B packet for remote blocks
        unsigned long long pkt =
            ((unsigned long long)(unsigned int)(s + 1) << 32) | __float_as_uint(hst);
        unsigned long long* dst = hx_grp + (size_t)((s + 1) & 1) * slotStride +
                                  (size_t)js * 128 + jl * 4 + b;
        __hip_atomic_store(dst, pkt, __ATOMIC_RELAXED, __HIP_MEMORY_SCOPE_AGENT);
        // own-slice bypass: next step's LDS buffer gets h directly
        ((float*)&hS[(s + 1) & 1][0])[j * 4 + b] = hst;
      }
      out[((size_t)t * B + batch) * 512 + d * 256 + j] = m ? hst : 0.0f;
    }
  }
}

// ---------------------------------------------------------------------------
// Viterbi: one block (one wave) per batch element. (unchanged)
// ---------------------------------------------------------------------------
__global__ __launch_bounds__(64) void viterbi_k(
    const float* __restrict__ em, const int* __restrict__ lengths,
    const float* __restrict__ startT, const float* __restrict__ endT,
    const float* __restrict__ trans, int* __restrict__ hist,
    int* __restrict__ outTags, int T, int B) {
  __shared__ float tr[NTAG * NTAG];
  __shared__ float sc[NTAG];
  __shared__ float ns[NTAG];
  int b = blockIdx.x;
  int j = threadIdx.x;
  for (int i = j; i < NTAG * NTAG; i += 64) tr[i] = trans[i];
  int len = lengths[b];
  if (j < NTAG) sc[j] = startT[j] + em[(size_t)b * NTAG + j];
  __syncthreads();
  for (int t = 1; t < T; ++t) {
    if (j < NTAG) {
      float best = -3.0e38f;
      int arg = 0;
      for (int i = 0; i < NTAG; ++i) {
        float v = sc[i] + tr[i * NTAG + j];
        if (v > best) { best = v; arg = i; }
      }
      bool m = t < len;
      float e = em[((size_t)t * B + b) * NTAG + j];
      ns[j] = m ? (best + e) : sc[j];
      hist[((size_t)(t - 1) * B + b) * NTAG + j] = m ? arg : j;
    }
    __syncthreads();
    if (j < NTAG) sc[j] = ns[j];
    __syncthreads();
  }
  if (j == 0) {
    float best = -3.0e38f;
    int arg = 0;
    for (int i = 0; i < NTAG; ++i) {
      float v = sc[i] + endT[i];
      if (v > best) { best = v; arg = i; }
    }
    int tag = arg;
    outTags[(size_t)(T - 1) * B + b] = (T - 1 < len) ? tag : 0;
    for (int t = T - 2; t >= 0; --t) {
      tag = hist[((size_t)t * B + b) * NTAG + tag];
      outTags[(size_t)t * B + b] = (t < len) ? tag : 0;
    }
  }
}

extern "C" void kernel_launch(void* const* d_in, const int* in_sizes, int n_in,
                              void* d_out, int out_size, void* d_ws, size_t ws_size,
                              hipStream_t stream) {
  const int* x = (const int*)d_in[0];
  const int* lens = (const int*)d_in[1];
  const float* embed = (const float*)d_in[2];
  const float* w_ih0 = (const float*)d_in[3];
  const float* w_hh0 = (const float*)d_in[4];
  const float* b_ih0 = (const float*)d_in[5];
  const float* b_hh0 = (const float*)d_in[6];
  const float* w_ih1 = (const float*)d_in[7];
  const float* w_hh1 = (const float*)d_in[8];
  const float* b_ih1 = (const float*)d_in[9];
  const float* b_hh1 = (const float*)d_in[10];
  const float* w_lin = (const float*)d_in[11];
  const float* b_lin = (const float*)d_in[12];
  const float* startT = (const float*)d_in[13];
  const float* endT = (const float*)d_in[14];
  const float* trans = (const float*)d_in[15];
  int* outTags = (int*)d_out;

  const int T = TT, B = BB;
  const int M = T * B;

  char* ws = (char*)d_ws;
  const size_t SZ_XP = 2ull * M * 1024 * 4;
  const size_t SZ_H = (size_t)M * 512 * 4;
  const size_t SZ_EM = (size_t)M * NTAG * 4;
  const size_t SZ_HIST = (size_t)M * NTAG * 4;
  float* xp = (float*)(ws);
  float* h0 = (float*)(ws + SZ_XP);
  float* h1 = (float*)(ws + SZ_XP + SZ_H);
  float* em = (float*)(ws + SZ_XP + 2 * SZ_H);
  int* hist = (int*)(ws + SZ_XP + 2 * SZ_H + SZ_EM);
  unsigned long long* hx0 = (unsigned long long*)(ws + SZ_XP + 2 * SZ_H + SZ_EM + SZ_HIST);
  unsigned long long* hx1 = hx0 + 2ull * 2 * 16 * 1024;
  // No memset needed: 0xAA poison never matches a stamp value 1..255.

  // 1. Layer-0 input projection (fused embedding gather)
  gemm_k<<<dim3(M / 64, 32), 256, 0, stream>>>(embed, x, w_ih0, b_ih0, b_hh0,
                                               xp, M, 256, 2048, 1);
  // 2. Layer-0 recurrence
  lstm_fused4<<<256, 512, 0, stream>>>(xp, w_hh0, lens, h0, hx0, T, B);

  // 3. Layer-1 input projection
  gemm_k<<<dim3(M / 64, 32), 256, 0, stream>>>(h0, nullptr, w_ih1, b_ih1, b_hh1,
                                               xp, M, 512, 2048, 1);
  // 4. Layer-1 recurrence
  lstm_fused4<<<256, 512, 0, stream>>>(xp, w_hh1, lens, h1, hx1, T, B);

  // 5. Emissions
  gemm_k<<<dim3(M / 64, 1), 256, 0, stream>>>(h1, nullptr, w_lin, b_lin, nullptr,
                                              em, M, 512, 34, 0);
  // 6. Viterbi decode
  viterbi_k<<<64, 64, 0, stream>>>(em, lens, startT, endT, trans, hist, outTags,
                                   T, B);
  (void)in_sizes; (void)n_in; (void)out_size; (void)ws_size;
}

// Round 7
// 2748.367 us; speedup vs baseline: 1.4626x; 1.4626x over previous
//
#include <hip/hip_runtime.h>
#include <cstddef>
#include <cstdint>

// Problem constants
#define TT 256
#define BB 64
#define NTAG 34
// M = TT*BB = 16384

__device__ __forceinline__ float sigf(float x) { return 1.0f / (1.0f + expf(-x)); }

// ---------------------------------------------------------------------------
// fp32 tiled GEMM v2: out[m][n] = sum_k A[m][k]*W[n][k] + biasA[n] (+biasB[n])
// BM=BN=128, BK=16, 256 threads, 8x8 micro-tile (64 FMA per 4 ds_read_b128 —
// 4x the FMA:LDS ratio of the old 64x64/4x4 kernel, which ran at ~41% of the
// 157 TF vector peak). A rows optionally gathered via gidx (embedding).
// xp_mode=1: store to xp[dir][m][1024] (dir = n>>10, constant per block).
// ---------------------------------------------------------------------------
__global__ __launch_bounds__(256) void gemm_k(
    const float* __restrict__ Abase, const int* __restrict__ gidx,
    const float* __restrict__ W, const float* __restrict__ biasA,
    const float* __restrict__ biasB, float* __restrict__ out,
    int M, int K, int Nvalid, int xp_mode) {
  __shared__ float As[16][132];  // [k][m], +4 pad keeps 16B align, 2-way max
  __shared__ float Bs[16][132];  // [k][n]
  int tid = threadIdx.x;
  int m0 = blockIdx.x * 128;
  int n0 = blockIdx.y * 128;
  int tx = tid & 15, ty = tid >> 4;  // 16x16 threads of 8x8 results

  // Staging mapping: float4 id f = tid (+256); row = f>>2 (0..63, +64), c4 = f&3
  int srow = tid >> 2;
  int c4 = tid & 3;

  float acc[8][8];
#pragma unroll
  for (int i = 0; i < 8; ++i)
#pragma unroll
    for (int j = 0; j < 8; ++j) acc[i][j] = 0.0f;

  const float* a0p;
  const float* a1p;
  {
    int ma = m0 + srow, mb = m0 + srow + 64;
    size_t ra = gidx ? (size_t)gidx[ma] : (size_t)ma;
    size_t rb = gidx ? (size_t)gidx[mb] : (size_t)mb;
    a0p = Abase + ra * (size_t)K + c4 * 4;
    a1p = Abase + rb * (size_t)K + c4 * 4;
  }
  int nA = n0 + srow, nB = n0 + srow + 64;
  const float* b0p = W + (size_t)nA * K + c4 * 4;
  const float* b1p = W + (size_t)nB * K + c4 * 4;
  bool v0 = nA < Nvalid, v1 = nB < Nvalid;

  for (int k0 = 0; k0 < K; k0 += 16) {
    float4 a0 = *(const float4*)(a0p + k0);
    float4 a1 = *(const float4*)(a1p + k0);
    float4 b0 = v0 ? *(const float4*)(b0p + k0) : make_float4(0, 0, 0, 0);
    float4 b1 = v1 ? *(const float4*)(b1p + k0) : make_float4(0, 0, 0, 0);
    __syncthreads();  // previous iteration's compute done before overwrite
    {
      int kb = c4 * 4;
      As[kb + 0][srow] = a0.x; As[kb + 1][srow] = a0.y;
      As[kb + 2][srow] = a0.z; As[kb + 3][srow] = a0.w;
      As[kb + 0][srow + 64] = a1.x; As[kb + 1][srow + 64] = a1.y;
      As[kb + 2][srow + 64] = a1.z; As[kb + 3][srow + 64] = a1.w;
      Bs[kb + 0][srow] = b0.x; Bs[kb + 1][srow] = b0.y;
      Bs[kb + 2][srow] = b0.z; Bs[kb + 3][srow] = b0.w;
      Bs[kb + 0][srow + 64] = b1.x; Bs[kb + 1][srow + 64] = b1.y;
      Bs[kb + 2][srow + 64] = b1.z; Bs[kb + 3][srow + 64] = b1.w;
    }
    __syncthreads();
#pragma unroll
    for (int k = 0; k < 16; ++k) {
      float4 av0 = *(const float4*)&As[k][ty * 8];
      float4 av1 = *(const float4*)&As[k][ty * 8 + 4];
      float4 bv0 = *(const float4*)&Bs[k][tx * 8];
      float4 bv1 = *(const float4*)&Bs[k][tx * 8 + 4];
      float a[8] = {av0.x, av0.y, av0.z, av0.w, av1.x, av1.y, av1.z, av1.w};
      float b[8] = {bv0.x, bv0.y, bv0.z, bv0.w, bv1.x, bv1.y, bv1.z, bv1.w};
#pragma unroll
      for (int i = 0; i < 8; ++i)
#pragma unroll
        for (int j = 0; j < 8; ++j) acc[i][j] += a[i] * b[j];
    }
  }

  // Epilogue: bias + store
  float bsum[8];
#pragma unroll
  for (int j = 0; j < 8; ++j) {
    int n = n0 + tx * 8 + j;
    bsum[j] = (n < Nvalid) ? (biasA[n] + (biasB ? biasB[n] : 0.0f)) : 0.0f;
  }
  if (xp_mode) {
    // whole block lies in one dir (n0 multiple of 128, dirs split at 1024)
    int dir = n0 >> 10;
    int noff = (n0 & 1023) + tx * 8;
#pragma unroll
    for (int i = 0; i < 8; ++i) {
      int m = m0 + ty * 8 + i;
      float* orow = out + ((size_t)dir * M + m) * 1024 + noff;
      float4 r0 = make_float4(acc[i][0] + bsum[0], acc[i][1] + bsum[1],
                              acc[i][2] + bsum[2], acc[i][3] + bsum[3]);
      float4 r1 = make_float4(acc[i][4] + bsum[4], acc[i][5] + bsum[5],
                              acc[i][6] + bsum[6], acc[i][7] + bsum[7]);
      *(float4*)(orow) = r0;
      *(float4*)(orow + 4) = r1;
    }
  } else {
#pragma unroll
    for (int i = 0; i < 8; ++i) {
      int m = m0 + ty * 8 + i;
#pragma unroll
      for (int j = 0; j < 8; ++j) {
        int n = n0 + tx * 8 + j;
        if (n < Nvalid) out[(size_t)m * Nvalid + n] = acc[i][j] + bsum[j];
      }
    }
  }
}

// ---------------------------------------------------------------------------
// Register-stationary LSTM recurrence, v3.1 (= verified v3 + fused poll).
// 256 blocks x 512 threads = 2 dir x 8 unit-slices(32 units) x 16 bg(4 batch).
// Exchange: 8-byte stamp-embedded packets via agent-scope RELAXED atomics —
// the L3 is the only legal cross-block medium (round 6 proved sc0/L2
// exchange loses stores to stale reader L2s; rounds 2 proved acquire/release
// causes L2 writeback-invalidate storms). v3.1 fuses the two serial packet
// polls into one round (both loads in flight) and issues the packet store
// before the scattered out store.
// ---------------------------------------------------------------------------
__global__ __launch_bounds__(512) void lstm_fused3(
    const float* __restrict__ xp,    // [2][M][1024]
    const float* __restrict__ whh,   // [2][1024][256]
    const int* __restrict__ lengths,
    float* __restrict__ out,         // [M][512]
    unsigned long long* hx,          // [2 slot][2 d][16 bg][1024 packets]
    int T, int B) {
  __shared__ float4 hS[256];   // h[k] for 4 batches
  __shared__ float xgS[512];   // [b][g][jl]
  int blk = blockIdx.x;
  int js = blk >> 5;
  int inner = blk & 31;
  int d = inner >> 4;
  int bg = inner & 15;
  int tid = threadIdx.x;
  int jl = tid >> 4, kseg = tid & 15;
  int j = js * 32 + jl;
  size_t M = (size_t)T * B;
  int b0 = bg * 4;

  // Stationary weights: w[g][i] = whh[d][g*256+j][kseg+16i]
  float w[4][16];
#pragma unroll
  for (int g = 0; g < 4; ++g) {
    const float* wr = whh + ((size_t)d * 1024 + g * 256 + j) * 256 + kseg;
#pragma unroll
    for (int i = 0; i < 16; ++i) w[g][i] = wr[16 * i];
  }

  int batch = b0 + (kseg & 3);
  int len = lengths[batch];
  float cst = 0.0f, hst = 0.0f;

  unsigned long long* hx_grp = hx + ((size_t)d * 16 + bg) * 1024;
  const size_t slotStride = (size_t)2 * 16 * 1024;  // packets per slot

  // xg loader mapping: tid -> (lb, lg, lj)
  int lb = tid >> 7, lg = (tid >> 5) & 3, lj = tid & 31;
  const float* xg_base = xp + (size_t)d * M * 1024 + (size_t)lg * 256 + js * 32 + lj;

  for (int s = 0; s < T; ++s) {
    int t = d ? (T - 1 - s) : s;
    // xp gate bias for this step (h-independent; overlaps poll latency)
    float xv = xg_base[((size_t)t * B + b0 + lb) * 1024];
    if (s == 0) {
      if (tid < 256) hS[tid] = make_float4(0.f, 0.f, 0.f, 0.f);
    } else {
      const unsigned long long* src = hx_grp + (size_t)(s & 1) * slotStride;
      unsigned int want = (unsigned int)s;
      unsigned long long p0, p1;
      int guard = 0;
      for (;;) {
        p0 = __hip_atomic_load(src + tid, __ATOMIC_RELAXED, __HIP_MEMORY_SCOPE_AGENT);
        p1 = __hip_atomic_load(src + 512 + tid, __ATOMIC_RELAXED, __HIP_MEMORY_SCOPE_AGENT);
        if ((unsigned int)(p0 >> 32) == want && (unsigned int)(p1 >> 32) == want)
          break;
        if (++guard > (1 << 22)) break;  // hang-preventer
      }
      ((float*)hS)[tid] = __uint_as_float((unsigned int)p0);
      ((float*)hS)[512 + tid] = __uint_as_float((unsigned int)p1);
    }
    xgS[tid] = xv;
    __syncthreads();

    // GEMV over my 16 k values for 4 gates x 4 batches
    float acc[4][4];
#pragma unroll
    for (int g = 0; g < 4; ++g)
#pragma unroll
      for (int b = 0; b < 4; ++b) acc[g][b] = 0.0f;
#pragma unroll
    for (int i = 0; i < 16; ++i) {
      float4 hv = hS[kseg + 16 * i];  // 2-way/bank broadcast = free
#pragma unroll
      for (int g = 0; g < 4; ++g) {
        acc[g][0] += w[g][i] * hv.x;
        acc[g][1] += w[g][i] * hv.y;
        acc[g][2] += w[g][i] * hv.z;
        acc[g][3] += w[g][i] * hv.w;
      }
    }
    // Butterfly over the 16 kseg lanes -> every lane holds full sums
#pragma unroll
    for (int g = 0; g < 4; ++g)
#pragma unroll
      for (int b = 0; b < 4; ++b) {
        float v = acc[g][b];
        v += __shfl_xor(v, 1);
        v += __shfl_xor(v, 2);
        v += __shfl_xor(v, 4);
        v += __shfl_xor(v, 8);
        acc[g][b] = v;
      }

    if (kseg < 4) {
      int b = kseg;
      float ig = sigf(acc[0][b] + xgS[b * 128 + 0 * 32 + jl]);
      float fg = sigf(acc[1][b] + xgS[b * 128 + 1 * 32 + jl]);
      float gg = tanhf(acc[2][b] + xgS[b * 128 + 2 * 32 + jl]);
      float og = sigf(acc[3][b] + xgS[b * 128 + 3 * 32 + jl]);
      bool m = t < len;
      float cn = fg * cst + ig * gg;
      float hn = og * tanhf(cn);
      if (m) { cst = cn; hst = hn; }
      if (s + 1 < T) {
        // critical packet store first (stamp-embedded, single-copy atomic 8B)
        unsigned long long pkt =
            ((unsigned long long)(unsigned int)(s + 1) << 32) | __float_as_uint(hst);
        unsigned long long* dst = hx_grp + (size_t)((s + 1) & 1) * slotStride +
                                  (size_t)js * 128 + jl * 4 + b;
        __hip_atomic_store(dst, pkt, __ATOMIC_RELAXED, __HIP_MEMORY_SCOPE_AGENT);
      }
      out[((size_t)t * B + batch) * 512 + d * 256 + j] = m ? hst : 0.0f;
    }
    __syncthreads();  // all reads of hS/xgS done before next-iter overwrite
  }
}

// ---------------------------------------------------------------------------
// Viterbi: one block (one wave) per batch element. (unchanged)
// ---------------------------------------------------------------------------
__global__ __launch_bounds__(64) void viterbi_k(
    const float* __restrict__ em, const int* __restrict__ lengths,
    const float* __restrict__ startT, const float* __restrict__ endT,
    const float* __restrict__ trans, int* __restrict__ hist,
    int* __restrict__ outTags, int T, int B) {
  __shared__ float tr[NTAG * NTAG];
  __shared__ float sc[NTAG];
  __shared__ float ns[NTAG];
  int b = blockIdx.x;
  int j = threadIdx.x;
  for (int i = j; i < NTAG * NTAG; i += 64) tr[i] = trans[i];
  int len = lengths[b];
  if (j < NTAG) sc[j] = startT[j] + em[(size_t)b * NTAG + j];
  __syncthreads();
  for (int t = 1; t < T; ++t) {
    if (j < NTAG) {
      float best = -3.0e38f;
      int arg = 0;
      for (int i = 0; i < NTAG; ++i) {
        float v = sc[i] + tr[i * NTAG + j];
        if (v > best) { best = v; arg = i; }
      }
      bool m = t < len;
      float e = em[((size_t)t * B + b) * NTAG + j];
      ns[j] = m ? (best + e) : sc[j];
      hist[((size_t)(t - 1) * B + b) * NTAG + j] = m ? arg : j;
    }
    __syncthreads();
    if (j < NTAG) sc[j] = ns[j];
    __syncthreads();
  }
  if (j == 0) {
    float best = -3.0e38f;
    int arg = 0;
    for (int i = 0; i < NTAG; ++i) {
      float v = sc[i] + endT[i];
      if (v > best) { best = v; arg = i; }
    }
    int tag = arg;
    outTags[(size_t)(T - 1) * B + b] = (T - 1 < len) ? tag : 0;
    for (int t = T - 2; t >= 0; --t) {
      tag = hist[((size_t)t * B + b) * NTAG + tag];
      outTags[(size_t)t * B + b] = (t < len) ? tag : 0;
    }
  }
}

extern "C" void kernel_launch(void* const* d_in, const int* in_sizes, int n_in,
                              void* d_out, int out_size, void* d_ws, size_t ws_size,
                              hipStream_t stream) {
  const int* x = (const int*)d_in[0];
  const int* lens = (const int*)d_in[1];
  const float* embed = (const float*)d_in[2];
  const float* w_ih0 = (const float*)d_in[3];
  const float* w_hh0 = (const float*)d_in[4];
  const float* b_ih0 = (const float*)d_in[5];
  const float* b_hh0 = (const float*)d_in[6];
  const float* w_ih1 = (const float*)d_in[7];
  const float* w_hh1 = (const float*)d_in[8];
  const float* b_ih1 = (const float*)d_in[9];
  const float* b_hh1 = (const float*)d_in[10];
  const float* w_lin = (const float*)d_in[11];
  const float* b_lin = (const float*)d_in[12];
  const float* startT = (const float*)d_in[13];
  const float* endT = (const float*)d_in[14];
  const float* trans = (const float*)d_in[15];
  int* outTags = (int*)d_out;

  const int T = TT, B = BB;
  const int M = T * B;

  char* ws = (char*)d_ws;
  const size_t SZ_XP = 2ull * M * 1024 * 4;
  const size_t SZ_H = (size_t)M * 512 * 4;
  const size_t SZ_EM = (size_t)M * NTAG * 4;
  const size_t SZ_HIST = (size_t)M * NTAG * 4;
  float* xp = (float*)(ws);
  float* h0 = (float*)(ws + SZ_XP);
  float* h1 = (float*)(ws + SZ_XP + SZ_H);
  float* em = (float*)(ws + SZ_XP + 2 * SZ_H);
  int* hist = (int*)(ws + SZ_XP + 2 * SZ_H + SZ_EM);
  unsigned long long* hx0 = (unsigned long long*)(ws + SZ_XP + 2 * SZ_H + SZ_EM + SZ_HIST);
  unsigned long long* hx1 = hx0 + 2ull * 2 * 16 * 1024;
  // No memset needed: 0xAA poison never matches a stamp value 1..255.

  // 1. Layer-0 input projection (fused embedding gather)
  gemm_k<<<dim3(M / 128, 16), 256, 0, stream>>>(embed, x, w_ih0, b_ih0, b_hh0,
                                                xp, M, 256, 2048, 1);
  // 2. Layer-0 recurrence
  lstm_fused3<<<256, 512, 0, stream>>>(xp, w_hh0, lens, h0, hx0, T, B);

  // 3. Layer-1 input projection
  gemm_k<<<dim3(M / 128, 16), 256, 0, stream>>>(h0, nullptr, w_ih1, b_ih1, b_hh1,
                                                xp, M, 512, 2048, 1);
  // 4. Layer-1 recurrence
  lstm_fused3<<<256, 512, 0, stream>>>(xp, w_hh1, lens, h1, hx1, T, B);

  // 5. Emissions
  gemm_k<<<dim3(M / 128, 1), 256, 0, stream>>>(h1, nullptr, w_lin, b_lin, nullptr,
                                               em, M, 512, 34, 0);
  // 6. Viterbi decode
  viterbi_k<<<64, 64, 0, stream>>>(em, lens, startT, endT, trans, hist, outTags,
                                   T, B);
  (void)in_sizes; (void)n_in; (void)out_size; (void)ws_size;
}